// Round 9
// baseline (624.136 us; speedup 1.0000x reference)
//
#include <hip/hip_runtime.h>
#include <math.h>

#define NEG_SLOPE 0.2f

typedef float f4 __attribute__((ext_vector_type(4)));
typedef __attribute__((ext_vector_type(8))) short short8;   // 8 bf16 (4 VGPRs)
typedef __attribute__((ext_vector_type(4))) float f32x4;
typedef unsigned short ushort_t;
typedef unsigned char uchar_t;

__device__ __forceinline__ unsigned short f2bf(float f) {
    unsigned u; __builtin_memcpy(&u, &f, 4);
    u = (u + 0x7FFFu + ((u >> 16) & 1u)) >> 16;   // RNE
    return (unsigned short)u;
}
__device__ __forceinline__ void gload16(const void* g, void* l) {
    __builtin_amdgcn_global_load_lds((const __attribute__((address_space(1))) void*)g,
                                     (__attribute__((address_space(3))) void*)l, 16, 0, 0);
}
__device__ __forceinline__ void cvt4(unsigned u, float& a, float& b, float& c, float& d) {
    asm("v_cvt_f32_ubyte0 %0, %1" : "=v"(a) : "v"(u));
    asm("v_cvt_f32_ubyte1 %0, %1" : "=v"(b) : "v"(u));
    asm("v_cvt_f32_ubyte2 %0, %1" : "=v"(c) : "v"(u));
    asm("v_cvt_f32_ubyte3 %0, %1" : "=v"(d) : "v"(u));
}

// ---------------- prep: casts + transposes + degree histogram ----------------
__global__ void prep_kernel(const float* __restrict__ x, const float* __restrict__ W1,
                            const float* __restrict__ W2, ushort_t* __restrict__ xb,
                            ushort_t* __restrict__ W1t, ushort_t* __restrict__ W2t,
                            const int* __restrict__ ei, int* __restrict__ deg,
                            int n_x, int pad_x, int E, int Et) {
    int i = blockIdx.x * blockDim.x + threadIdx.x;
    if (i < Et) {
        int d = (i < E) ? ei[E + i] : (i - E);
        atomicAdd(&deg[d], 1);
    }
    if (i < pad_x) {
        xb[i] = f2bf(i < n_x ? x[i] : 0.f);
        return;
    }
    int k = i - pad_x;
    if (k < 128 * 512) {                 // W1 [128][512] -> W1t [512][128]
        int r = k >> 9, c = k & 511;
        W1t[(size_t)c * 128 + r] = f2bf(W1[k]);
        return;
    }
    k -= 128 * 512;
    if (k < 512 * 128) {                 // W2 [512][128] -> W2t [128][512]
        int r = k >> 7, c = k & 127;
        W2t[(size_t)c * 512 + r] = f2bf(W2[k]);
    }
}

// ---------------- scan ----------------
__global__ __launch_bounds__(1024) void scan_local(const int* __restrict__ deg,
                                                   int* __restrict__ off,
                                                   int* __restrict__ btot, int n) {
    __shared__ int s_w[16];
    int tid = threadIdx.x, lane = tid & 63, wv = tid >> 6;
    int i = blockIdx.x * 1024 + tid;
    int v = (i < n) ? deg[i] : 0;
    int x = v;
    #pragma unroll
    for (int d = 1; d < 64; d <<= 1) {
        int y = __shfl_up(x, d);
        if (lane >= d) x += y;
    }
    if (lane == 63) s_w[wv] = x;
    __syncthreads();
    if (tid < 16) {
        int y = s_w[tid];
        int z = y;
        #pragma unroll
        for (int d = 1; d < 16; d <<= 1) {
            int t2 = __shfl_up(z, d);
            if (tid >= d) z += t2;
        }
        if (tid == 15) btot[blockIdx.x] = z;
        s_w[tid] = z - y;
    }
    __syncthreads();
    if (i < n) off[i] = s_w[wv] + (x - v);
}

__global__ __launch_bounds__(256) void scan_add(const int* __restrict__ btot,
                                                int* __restrict__ off,
                                                int* __restrict__ cur,
                                                const int* __restrict__ batch,
                                                int* __restrict__ gcnt, int n, int nb) {
    __shared__ int s_b[2];
    int i = blockIdx.x * 256 + threadIdx.x;
    if (threadIdx.x < 64) {
        int lane = threadIdx.x;
        int v = (lane < nb) ? btot[lane] : 0;
        int x = v;
        #pragma unroll
        for (int d = 1; d < 64; d <<= 1) {
            int y = __shfl_up(x, d);
            if (lane >= d) x += y;
        }
        int c = blockIdx.x >> 2;
        int base = (c == 0) ? 0 : __shfl(x, c - 1);
        int total = __shfl(x, nb - 1);
        if (lane == 0) { s_b[0] = base; s_b[1] = total; }
    }
    __syncthreads();
    if (i < n) {
        int o = off[i] + s_b[0];
        off[i] = o;
        cur[i] = o;
        atomicAdd(&gcnt[batch[i]], 1);
    } else if (i == n) {
        off[n] = s_b[1];
    }
}

__global__ void scatter_kernel(const int* __restrict__ ei, int E, int Et,
                               int* __restrict__ cur, int* __restrict__ csr) {
    int e = blockIdx.x * blockDim.x + threadIdx.x;
    if (e >= Et) return;
    int s, d;
    if (e < E) { s = ei[e]; d = ei[E + e]; }
    else       { s = d = e - E; }
    int p = atomicAdd(&cur[d], 1);
    csr[p] = s;
}

// ---------------- bf16 MFMA GEMM, BM x 128 tile, per-(row,head) int8 quant ----------------
// Cq written HEAD-MAJOR: Cq[(hb*Mpad + node)*128 + c]. side[(node*H+hb)*2] = {avs, sc}.
template<int MI, int H>
__global__ __launch_bounds__(256) void gemm_q(const ushort_t* __restrict__ A,
                                              const ushort_t* __restrict__ Bt,
                                              uchar_t* __restrict__ Cq,
                                              const float* __restrict__ aw_src,
                                              const float* __restrict__ aw_dst,
                                              float* __restrict__ side,
                                              float* __restrict__ avd,
                                              int K, int Mpad) {
    constexpr int BM = MI * 32;
    constexpr int AI = MI / 2;           // A staging insts per wave (16 rows each)
    __shared__ __align__(16) ushort_t As[BM * 32];
    __shared__ __align__(16) ushort_t Bs[128 * 32];
    __shared__ float s_red[3][2][BM];          // [rowmax|ps|pd][wc][row]
    __shared__ float s_rs[BM];
    __shared__ __align__(16) uchar_t s_q[BM * 144];
    const int t = threadIdx.x, w = t >> 6, lane = t & 63;
    const int r0 = blockIdx.x * BM, hb = blockIdx.y, c0 = hb * 128;
    const int wr = w & 1, wc = w >> 1;

    const ushort_t* Ag = A + (size_t)(r0 + w * (BM / 4) + (lane >> 2)) * K + (lane & 3) * 8;
    const ushort_t* Bg = Bt + (size_t)(c0 + w * 32 + (lane >> 2)) * K + (lane & 3) * 8;
    ushort_t* Al = As + w * (BM / 4) * 32;
    ushort_t* Bl = Bs + w * 1024;

    f32x4 acc[MI][4] = {};
    for (int k0 = 0; k0 < K; k0 += 32) {
        __syncthreads();
        #pragma unroll
        for (int m = 0; m < AI; m++) gload16(Ag + k0 + (size_t)m * 16 * K, Al + m * 512);
        gload16(Bg + k0, Bl);
        gload16(Bg + k0 + (size_t)16 * K, Bl + 512);
        __syncthreads();
        short8 af[MI], bf[4];
        #pragma unroll
        for (int i = 0; i < MI; i++)
            af[i] = *(const short8*)(As + (wr * MI * 16 + i * 16 + (lane & 15)) * 32 + (lane >> 4) * 8);
        #pragma unroll
        for (int jj = 0; jj < 4; jj++)
            bf[jj] = *(const short8*)(Bs + (wc * 64 + jj * 16 + (lane & 15)) * 32 + (lane >> 4) * 8);
        #pragma unroll
        for (int i = 0; i < MI; i++)
            #pragma unroll
            for (int jj = 0; jj < 4; jj++)
                acc[i][jj] = __builtin_amdgcn_mfma_f32_16x16x32_bf16(af[i], bf[jj], acc[i][jj], 0, 0, 0);
    }

    float asc[4], adc[4];
    #pragma unroll
    for (int jj = 0; jj < 4; jj++) {
        int c = c0 + wc * 64 + jj * 16 + (lane & 15);
        asc[jj] = aw_src[c];
        adc[jj] = aw_dst[c];
    }
    #pragma unroll
    for (int i = 0; i < MI; i++) {
        #pragma unroll
        for (int r = 0; r < 4; r++) {
            float m = 0.f, ps = 0.f, pd = 0.f;
            #pragma unroll
            for (int jj = 0; jj < 4; jj++) {
                float v = acc[i][jj][r];
                m = fmaxf(m, fabsf(v));
                ps = fmaf(v, asc[jj], ps);
                pd = fmaf(v, adc[jj], pd);
            }
            #pragma unroll
            for (int d = 1; d < 16; d <<= 1) {
                m = fmaxf(m, __shfl_xor(m, d));
                ps += __shfl_xor(ps, d);
                pd += __shfl_xor(pd, d);
            }
            if ((lane & 15) == 0) {
                int row = wr * MI * 16 + i * 16 + (lane >> 4) * 4 + r;
                s_red[0][wc][row] = m;
                s_red[1][wc][row] = ps;
                s_red[2][wc][row] = pd;
            }
        }
    }
    __syncthreads();
    if (t < BM) {
        float rm = fmaxf(fmaxf(s_red[0][0][t], s_red[0][1][t]), 1e-30f);
        s_rs[t] = 127.f / rm;
        int node = r0 + t;
        side[((size_t)node * H + hb) * 2]     = s_red[1][0][t] + s_red[1][1][t];
        side[((size_t)node * H + hb) * 2 + 1] = rm * (1.f / 127.f);
        avd[(size_t)node * H + hb]            = s_red[2][0][t] + s_red[2][1][t];
    }
    __syncthreads();
    #pragma unroll
    for (int i = 0; i < MI; i++)
        #pragma unroll
        for (int jj = 0; jj < 4; jj++)
            #pragma unroll
            for (int r = 0; r < 4; r++) {
                int row = wr * MI * 16 + i * 16 + (lane >> 4) * 4 + r;
                int col = wc * 64 + jj * 16 + (lane & 15);
                int qi = (int)rintf(acc[i][jj][r] * s_rs[row]) + 128;
                qi = min(255, max(0, qi));
                s_q[row * 144 + col] = (uchar_t)qi;
            }
    __syncthreads();
    #pragma unroll
    for (int p2 = 0; p2 < BM / 32; p2++) {
        int idx = p2 * 256 + t;
        int row = idx >> 3, ch = idx & 7;
        *(uint4*)(Cq + ((size_t)hb * Mpad + r0 + row) * 128 + ch * 16) =
            *(const uint4*)(s_q + row * 144 + ch * 16);
    }
}

// ---------------- layer-1 aggregation: one wave per (dst, head) ----------------
// fq head-major [4][Mpad][128]; grid (ceil(N/4), 4) so each XCD works one ~6.4MB
// head slice at a time (L2 locality). 8 lanes/row -> 1 dwordx4 inst = 8 edges.
__global__ __launch_bounds__(256) void agg_q1(const int* __restrict__ off,
                                              const int* __restrict__ csr,
                                              const uchar_t* __restrict__ fq,
                                              const float* __restrict__ side,
                                              const float* __restrict__ avd,
                                              const float* __restrict__ bias,
                                              ushort_t* __restrict__ outb,
                                              int n, int Mpad) {
    __shared__ float2 s_w[4][64];
    int w = threadIdx.x >> 6, lane = threadIdx.x & 63;
    int dst = blockIdx.x * 4 + w;
    int h = blockIdx.y;
    if (dst >= n) return;
    float adv = avd[(size_t)dst * 4 + h];
    int beg = off[dst], end = off[dst + 1];
    float den = 0.f, Ssum = 0.f;
    float acc[16] = {};
    float2* eww = s_w[w];
    const int slot = lane >> 3, sub8 = lane & 7;
    const uchar_t* fqh = fq + (size_t)h * Mpad * 128;

    for (int b = beg; b < end; b += 64) {
        int idx = b + lane;
        bool val = idx < end;
        int sv = val ? csr[idx] : 0;
        unsigned myoff = (unsigned)sv * 128;
        {
            float2 sp = *(const float2*)(side + ((size_t)sv * 4 + h) * 2);
            float l = sp.x + adv;
            l = fmaxf(l, l * NEG_SLOPE);
            float e = val ? __expf(l) : 0.f;
            eww[lane] = make_float2(e, e * sp.y);
        }
        asm volatile("s_waitcnt lgkmcnt(0)" ::: "memory");
        int cnt = min(64, end - b);
        int ng = (cnt + 7) >> 3;
        for (int g0 = 0; g0 < ng; g0 += 4) {
            uint4 bufs[4];
            int gm = min(4, ng - g0);
            #pragma unroll
            for (int g = 0; g < 4; g++) {
                if (g < gm) {
                    unsigned o = (unsigned)__shfl((int)myoff, (g0 + g) * 8 + slot);
                    bufs[g] = *(const uint4*)(fqh + o + sub8 * 16);
                }
            }
            #pragma unroll
            for (int g = 0; g < 4; g++) {
                if (g < gm) {
                    float2 ees = eww[(g0 + g) * 8 + slot];
                    den += ees.x; Ssum += ees.y;
                    float es = ees.y;
                    float b0, b1, b2, b3;
                    cvt4(bufs[g].x, b0, b1, b2, b3);
                    acc[0] = fmaf(es, b0, acc[0]);   acc[1] = fmaf(es, b1, acc[1]);
                    acc[2] = fmaf(es, b2, acc[2]);   acc[3] = fmaf(es, b3, acc[3]);
                    cvt4(bufs[g].y, b0, b1, b2, b3);
                    acc[4] = fmaf(es, b0, acc[4]);   acc[5] = fmaf(es, b1, acc[5]);
                    acc[6] = fmaf(es, b2, acc[6]);   acc[7] = fmaf(es, b3, acc[7]);
                    cvt4(bufs[g].z, b0, b1, b2, b3);
                    acc[8] = fmaf(es, b0, acc[8]);   acc[9] = fmaf(es, b1, acc[9]);
                    acc[10] = fmaf(es, b2, acc[10]); acc[11] = fmaf(es, b3, acc[11]);
                    cvt4(bufs[g].w, b0, b1, b2, b3);
                    acc[12] = fmaf(es, b0, acc[12]); acc[13] = fmaf(es, b1, acc[13]);
                    acc[14] = fmaf(es, b2, acc[14]); acc[15] = fmaf(es, b3, acc[15]);
                }
            }
        }
    }
    #pragma unroll
    for (int d = 8; d < 64; d <<= 1) {
        den += __shfl_xor(den, d);
        Ssum += __shfl_xor(Ssum, d);
    }
    #pragma unroll
    for (int u = 0; u < 16; u++) {
        #pragma unroll
        for (int d = 8; d < 64; d <<= 1) acc[u] += __shfl_xor(acc[u], d);
    }
    float rden = 1.f / den;
    if (lane < 8) {
        unsigned short ov[16];
        #pragma unroll
        for (int u = 0; u < 16; u++) {
            float v = (acc[u] - 128.f * Ssum) * rden + bias[h * 128 + lane * 16 + u];
            v = v > 0.f ? v : expm1f(v);
            ov[u] = f2bf(v);
        }
        ushort_t* op = outb + (size_t)dst * 512 + h * 128 + lane * 16;
        *(short8*)op = *(short8*)ov;
        *(short8*)(op + 8) = *(short8*)(ov + 8);
    }
}

// ---------------- layer-2 aggregation: one wave per dst (H=1), f32 out ----------------
__global__ __launch_bounds__(256) void agg_q2(const int* __restrict__ off,
                                              const int* __restrict__ csr,
                                              const uchar_t* __restrict__ fq,
                                              const float* __restrict__ side,
                                              const float* __restrict__ avd,
                                              const float* __restrict__ bias,
                                              float* __restrict__ outf, int n) {
    __shared__ float2 s_w[4][64];
    int w = threadIdx.x >> 6, lane = threadIdx.x & 63;
    int dst = blockIdx.x * 4 + w;
    if (dst >= n) return;
    float adv = avd[dst];
    int beg = off[dst], end = off[dst + 1];
    float den = 0.f, Ssum = 0.f;
    float acc[16] = {};
    float2* eww = s_w[w];
    const int slot = lane >> 3, sub8 = lane & 7;

    for (int b = beg; b < end; b += 64) {
        int idx = b + lane;
        bool val = idx < end;
        int sv = val ? csr[idx] : 0;
        unsigned myoff = (unsigned)sv * 128;
        {
            float2 sp = *(const float2*)(side + (size_t)sv * 2);
            float l = sp.x + adv;
            l = fmaxf(l, l * NEG_SLOPE);
            float e = val ? __expf(l) : 0.f;
            eww[lane] = make_float2(e, e * sp.y);
        }
        asm volatile("s_waitcnt lgkmcnt(0)" ::: "memory");
        int cnt = min(64, end - b);
        int ng = (cnt + 7) >> 3;
        for (int g0 = 0; g0 < ng; g0 += 4) {
            uint4 bufs[4];
            int gm = min(4, ng - g0);
            #pragma unroll
            for (int g = 0; g < 4; g++) {
                if (g < gm) {
                    unsigned o = (unsigned)__shfl((int)myoff, (g0 + g) * 8 + slot);
                    bufs[g] = *(const uint4*)(fq + o + sub8 * 16);
                }
            }
            #pragma unroll
            for (int g = 0; g < 4; g++) {
                if (g < gm) {
                    float2 ees = eww[(g0 + g) * 8 + slot];
                    den += ees.x; Ssum += ees.y;
                    float es = ees.y;
                    float b0, b1, b2, b3;
                    cvt4(bufs[g].x, b0, b1, b2, b3);
                    acc[0] = fmaf(es, b0, acc[0]);   acc[1] = fmaf(es, b1, acc[1]);
                    acc[2] = fmaf(es, b2, acc[2]);   acc[3] = fmaf(es, b3, acc[3]);
                    cvt4(bufs[g].y, b0, b1, b2, b3);
                    acc[4] = fmaf(es, b0, acc[4]);   acc[5] = fmaf(es, b1, acc[5]);
                    acc[6] = fmaf(es, b2, acc[6]);   acc[7] = fmaf(es, b3, acc[7]);
                    cvt4(bufs[g].z, b0, b1, b2, b3);
                    acc[8] = fmaf(es, b0, acc[8]);   acc[9] = fmaf(es, b1, acc[9]);
                    acc[10] = fmaf(es, b2, acc[10]); acc[11] = fmaf(es, b3, acc[11]);
                    cvt4(bufs[g].w, b0, b1, b2, b3);
                    acc[12] = fmaf(es, b0, acc[12]); acc[13] = fmaf(es, b1, acc[13]);
                    acc[14] = fmaf(es, b2, acc[14]); acc[15] = fmaf(es, b3, acc[15]);
                }
            }
        }
    }
    #pragma unroll
    for (int d = 8; d < 64; d <<= 1) {
        den += __shfl_xor(den, d);
        Ssum += __shfl_xor(Ssum, d);
    }
    #pragma unroll
    for (int u = 0; u < 16; u++) {
        #pragma unroll
        for (int d = 8; d < 64; d <<= 1) acc[u] += __shfl_xor(acc[u], d);
    }
    float rden = 1.f / den;
    if (lane < 8) {
        float ov[16];
        #pragma unroll
        for (int u = 0; u < 16; u++) {
            float v = (acc[u] - 128.f * Ssum) * rden + bias[lane * 16 + u];
            ov[u] = v > 0.f ? v : expm1f(v);
        }
        float* op = outf + (size_t)dst * 128 + lane * 16;
        #pragma unroll
        for (int q = 0; q < 4; q++)
            *(f4*)(op + q * 4) = *(f4*)(ov + q * 4);
    }
}

// ---------------- pooling (batch sorted -> run-compressed atomics) + head ----------------
__global__ __launch_bounds__(256) void pool_kernel(const float* __restrict__ feat,
                                                   const int* __restrict__ batch,
                                                   float* __restrict__ gsum, int n) {
    int t = threadIdx.x;
    int ch = t & 127, half = t >> 7;
    int base = blockIdx.x * 64;
    float acc = 0.f;
    int curg = -1;
    for (int k = half; k < 64; k += 2) {
        int node = base + k;
        if (node >= n) break;
        int g = batch[node];
        if (g != curg) {
            if (curg >= 0) atomicAdd(&gsum[(size_t)curg * 128 + ch], acc);
            acc = 0.f;
            curg = g;
        }
        acc += feat[(size_t)node * 128 + ch];
    }
    if (curg >= 0) atomicAdd(&gsum[(size_t)curg * 128 + ch], acc);
}

__global__ __launch_bounds__(256) void final_kernel(const float* __restrict__ gsum,
                                                    const int* __restrict__ gcnt,
                                                    const float* __restrict__ Wl,
                                                    const float* __restrict__ bl,
                                                    float* __restrict__ out, int g_total) {
    int w = threadIdx.x >> 6, lane = threadIdx.x & 63;
    int g = blockIdx.x * 4 + w;
    if (g >= g_total) return;
    float inv = 1.f / fmaxf((float)gcnt[g], 1.f);
    float p = 0.f;
    #pragma unroll
    for (int j = 0; j < 2; j++) {
        int ch = lane + 64 * j;
        p += gsum[(size_t)g * 128 + ch] * Wl[ch];
    }
    #pragma unroll
    for (int d = 32; d; d >>= 1) p += __shfl_xor(p, d);
    if (lane == 0) out[g] = p * inv + bl[0];
}

extern "C" void kernel_launch(void* const* d_in, const int* in_sizes, int n_in,
                              void* d_out, int out_size, void* d_ws, size_t ws_size,
                              hipStream_t stream) {
    const float* x   = (const float*)d_in[0];
    const int*   ei  = (const int*)d_in[1];
    const int*   bat = (const int*)d_in[2];
    const float* W1  = (const float*)d_in[3];
    const float* as1 = (const float*)d_in[4];
    const float* ad1 = (const float*)d_in[5];
    const float* b1  = (const float*)d_in[6];
    const float* W2  = (const float*)d_in[7];
    const float* as2 = (const float*)d_in[8];
    const float* ad2 = (const float*)d_in[9];
    const float* b2  = (const float*)d_in[10];
    const float* Wl  = (const float*)d_in[11];
    const float* bl  = (const float*)d_in[12];
    float* out = (float*)d_out;

    const int N    = in_sizes[0] / 128;
    const int E    = in_sizes[1] / 2;
    const int Et   = E + N;
    const int G    = 512;
    const int Mpad = (N + 127) & ~127;
    const int nb   = (N + 1023) >> 10;

    char* p = (char*)d_ws;
    auto alloc = [&](size_t bytes) { char* r = p; p += (bytes + 255) & ~(size_t)255; return r; };
    ushort_t* xb    = (ushort_t*)alloc((size_t)Mpad * 128 * 2);
    ushort_t* W1t   = (ushort_t*)alloc((size_t)512 * 128 * 2);
    ushort_t* W2t   = (ushort_t*)alloc((size_t)128 * 512 * 2);
    uchar_t*  h1q   = (uchar_t*)alloc((size_t)Mpad * 512);     // head-major [4][Mpad][128]
    ushort_t* hb    = (ushort_t*)alloc((size_t)Mpad * 512 * 2);
    uchar_t*  h2q   = (uchar_t*)alloc((size_t)Mpad * 128);
    float*    feat2 = (float*)alloc((size_t)N * 128 * 4);
    float*    side1 = (float*)alloc((size_t)Mpad * 8 * 4);     // [node][4]{avs,sc}
    float*    avd1  = (float*)alloc((size_t)Mpad * 4 * 4);
    float*    side2 = (float*)alloc((size_t)Mpad * 2 * 4);
    float*    avd2  = (float*)alloc((size_t)Mpad * 4);
    // ---- zeroed block (one memset) ----
    float*    gsum  = (float*)alloc((size_t)G * 128 * 4);
    int*      gcnt  = (int*)alloc((size_t)G * 4);
    int*      deg   = (int*)alloc((size_t)N * 4);
    // ---- end zeroed block ----
    int*      off   = (int*)alloc((size_t)(N + 1) * 4);
    int*      cur   = (int*)alloc((size_t)N * 4);
    int*      btot  = (int*)alloc((size_t)128 * 4);
    int*      csr   = (int*)alloc((size_t)Et * 4);

    hipMemsetAsync(gsum, 0, (size_t)((char*)off - (char*)gsum), stream);
    hipMemsetAsync(hb + (size_t)N * 512, 0, (size_t)(Mpad - N) * 512 * 2, stream);

    // prep (casts + degree hist), then CSR
    const int prep_n = Mpad * 128 + 2 * 65536;
    prep_kernel<<<(prep_n + 255) / 256, 256, 0, stream>>>(x, W1, W2, xb, W1t, W2t,
                                                          ei, deg, N * 128, Mpad * 128, E, Et);
    scan_local<<<nb, 1024, 0, stream>>>(deg, off, btot, N);
    scan_add<<<(N + 256) / 256, 256, 0, stream>>>(btot, off, cur, bat, gcnt, N, nb);
    scatter_kernel<<<(Et + 255) / 256, 256, 0, stream>>>(ei, E, Et, cur, csr);

    // Layer 1
    gemm_q<4, 4><<<dim3(Mpad / 128, 4), 256, 0, stream>>>(xb, W1t, h1q, as1, ad1, side1, avd1,
                                                          128, Mpad);
    agg_q1<<<dim3((N + 3) / 4, 4), 256, 0, stream>>>(off, csr, h1q, side1, avd1, b1, hb, N, Mpad);

    // Layer 2
    gemm_q<2, 1><<<dim3(Mpad / 64, 1), 256, 0, stream>>>(hb, W2t, h2q, as2, ad2, side2, avd2,
                                                         512, Mpad);
    agg_q2<<<(N + 3) / 4, 256, 0, stream>>>(off, csr, h2q, side2, avd2, b2, feat2, N);

    // Pool + head
    pool_kernel<<<(N + 63) / 64, 256, 0, stream>>>(feat2, bat, gsum, N);
    final_kernel<<<(G + 3) / 4, 256, 0, stream>>>(gsum, gcnt, Wl, bl, out, G);
}

// Round 10
// 425.475 us; speedup vs baseline: 1.4669x; 1.4669x over previous
//
#include <hip/hip_runtime.h>
#include <math.h>

#define NEG_SLOPE 0.2f

typedef float f4 __attribute__((ext_vector_type(4)));
typedef __attribute__((ext_vector_type(8))) short short8;   // 8 bf16 (4 VGPRs)
typedef __attribute__((ext_vector_type(4))) float f32x4;
typedef unsigned short ushort_t;
typedef unsigned char uchar_t;

__device__ __forceinline__ unsigned short f2bf(float f) {
    unsigned u; __builtin_memcpy(&u, &f, 4);
    u = (u + 0x7FFFu + ((u >> 16) & 1u)) >> 16;   // RNE
    return (unsigned short)u;
}
__device__ __forceinline__ void gload16(const void* g, void* l) {
    __builtin_amdgcn_global_load_lds((const __attribute__((address_space(1))) void*)g,
                                     (__attribute__((address_space(3))) void*)l, 16, 0, 0);
}
__device__ __forceinline__ void cvt4(unsigned u, float& a, float& b, float& c, float& d) {
    asm("v_cvt_f32_ubyte0 %0, %1" : "=v"(a) : "v"(u));
    asm("v_cvt_f32_ubyte1 %0, %1" : "=v"(b) : "v"(u));
    asm("v_cvt_f32_ubyte2 %0, %1" : "=v"(c) : "v"(u));
    asm("v_cvt_f32_ubyte3 %0, %1" : "=v"(d) : "v"(u));
}

// ---------------- prep: casts + transposes + degree histogram ----------------
__global__ void prep_kernel(const float* __restrict__ x, const float* __restrict__ W1,
                            const float* __restrict__ W2, ushort_t* __restrict__ xb,
                            ushort_t* __restrict__ W1t, ushort_t* __restrict__ W2t,
                            const int* __restrict__ ei, int* __restrict__ deg,
                            int n_x, int pad_x, int E, int Et) {
    int i = blockIdx.x * blockDim.x + threadIdx.x;
    if (i < Et) {
        int d = (i < E) ? ei[E + i] : (i - E);
        atomicAdd(&deg[d], 1);
    }
    if (i < pad_x) {
        xb[i] = f2bf(i < n_x ? x[i] : 0.f);
        return;
    }
    int k = i - pad_x;
    if (k < 128 * 512) {                 // W1 [128][512] -> W1t [512][128]
        int r = k >> 9, c = k & 511;
        W1t[(size_t)c * 128 + r] = f2bf(W1[k]);
        return;
    }
    k -= 128 * 512;
    if (k < 512 * 128) {                 // W2 [512][128] -> W2t [128][512]
        int r = k >> 7, c = k & 127;
        W2t[(size_t)c * 512 + r] = f2bf(W2[k]);
    }
}

// ---------------- scan ----------------
__global__ __launch_bounds__(1024) void scan_local(const int* __restrict__ deg,
                                                   int* __restrict__ off,
                                                   int* __restrict__ btot, int n) {
    __shared__ int s_w[16];
    int tid = threadIdx.x, lane = tid & 63, wv = tid >> 6;
    int i = blockIdx.x * 1024 + tid;
    int v = (i < n) ? deg[i] : 0;
    int x = v;
    #pragma unroll
    for (int d = 1; d < 64; d <<= 1) {
        int y = __shfl_up(x, d);
        if (lane >= d) x += y;
    }
    if (lane == 63) s_w[wv] = x;
    __syncthreads();
    if (tid < 16) {
        int y = s_w[tid];
        int z = y;
        #pragma unroll
        for (int d = 1; d < 16; d <<= 1) {
            int t2 = __shfl_up(z, d);
            if (tid >= d) z += t2;
        }
        if (tid == 15) btot[blockIdx.x] = z;
        s_w[tid] = z - y;
    }
    __syncthreads();
    if (i < n) off[i] = s_w[wv] + (x - v);
}

__global__ __launch_bounds__(256) void scan_add(const int* __restrict__ btot,
                                                int* __restrict__ off,
                                                int* __restrict__ cur,
                                                const int* __restrict__ batch,
                                                int* __restrict__ gcnt, int n, int nb) {
    __shared__ int s_b[2];
    int i = blockIdx.x * 256 + threadIdx.x;
    if (threadIdx.x < 64) {
        int lane = threadIdx.x;
        int v = (lane < nb) ? btot[lane] : 0;
        int x = v;
        #pragma unroll
        for (int d = 1; d < 64; d <<= 1) {
            int y = __shfl_up(x, d);
            if (lane >= d) x += y;
        }
        int c = blockIdx.x >> 2;
        int base = (c == 0) ? 0 : __shfl(x, c - 1);
        int total = __shfl(x, nb - 1);
        if (lane == 0) { s_b[0] = base; s_b[1] = total; }
    }
    __syncthreads();
    if (i < n) {
        int o = off[i] + s_b[0];
        off[i] = o;
        cur[i] = o;
        atomicAdd(&gcnt[batch[i]], 1);
    } else if (i == n) {
        off[n] = s_b[1];
    }
}

__global__ void scatter_kernel(const int* __restrict__ ei, int E, int Et,
                               int* __restrict__ cur, int* __restrict__ csr) {
    int e = blockIdx.x * blockDim.x + threadIdx.x;
    if (e >= Et) return;
    int s, d;
    if (e < E) { s = ei[e]; d = ei[E + e]; }
    else       { s = d = e - E; }
    int p = atomicAdd(&cur[d], 1);
    csr[p] = s;
}

// ---------------- bf16 MFMA GEMM, BM x 128 tile, per-(row,head) int8 quant ----------------
// MI = 16-row tiles per wave (MI=4 -> BM=128, MI=2 -> BM=64). Node-major Cq.
template<int MI, int H>
__global__ __launch_bounds__(256) void gemm_q(const ushort_t* __restrict__ A,
                                              const ushort_t* __restrict__ Bt,
                                              uchar_t* __restrict__ Cq,
                                              const float* __restrict__ aw_src,
                                              const float* __restrict__ aw_dst,
                                              float* __restrict__ side,
                                              float* __restrict__ avd,
                                              int K) {
    constexpr int BM = MI * 32;
    constexpr int AI = MI / 2;           // A staging insts per wave (16 rows each)
    const int Nc = H * 128;
    __shared__ __align__(16) ushort_t As[BM * 32];
    __shared__ __align__(16) ushort_t Bs[128 * 32];
    __shared__ float s_red[3][2][BM];          // [rowmax|ps|pd][wc][row]
    __shared__ float s_rs[BM];
    __shared__ __align__(16) uchar_t s_q[BM * 144];
    const int t = threadIdx.x, w = t >> 6, lane = t & 63;
    const int r0 = blockIdx.x * BM, hb = blockIdx.y, c0 = hb * 128;
    const int wr = w & 1, wc = w >> 1;

    const ushort_t* Ag = A + (size_t)(r0 + w * (BM / 4) + (lane >> 2)) * K + (lane & 3) * 8;
    const ushort_t* Bg = Bt + (size_t)(c0 + w * 32 + (lane >> 2)) * K + (lane & 3) * 8;
    ushort_t* Al = As + w * (BM / 4) * 32;
    ushort_t* Bl = Bs + w * 1024;

    f32x4 acc[MI][4] = {};
    for (int k0 = 0; k0 < K; k0 += 32) {
        __syncthreads();
        #pragma unroll
        for (int m = 0; m < AI; m++) gload16(Ag + k0 + (size_t)m * 16 * K, Al + m * 512);
        gload16(Bg + k0, Bl);
        gload16(Bg + k0 + (size_t)16 * K, Bl + 512);
        __syncthreads();
        short8 af[MI], bf[4];
        #pragma unroll
        for (int i = 0; i < MI; i++)
            af[i] = *(const short8*)(As + (wr * MI * 16 + i * 16 + (lane & 15)) * 32 + (lane >> 4) * 8);
        #pragma unroll
        for (int jj = 0; jj < 4; jj++)
            bf[jj] = *(const short8*)(Bs + (wc * 64 + jj * 16 + (lane & 15)) * 32 + (lane >> 4) * 8);
        #pragma unroll
        for (int i = 0; i < MI; i++)
            #pragma unroll
            for (int jj = 0; jj < 4; jj++)
                acc[i][jj] = __builtin_amdgcn_mfma_f32_16x16x32_bf16(af[i], bf[jj], acc[i][jj], 0, 0, 0);
    }

    float asc[4], adc[4];
    #pragma unroll
    for (int jj = 0; jj < 4; jj++) {
        int c = c0 + wc * 64 + jj * 16 + (lane & 15);
        asc[jj] = aw_src[c];
        adc[jj] = aw_dst[c];
    }
    #pragma unroll
    for (int i = 0; i < MI; i++) {
        #pragma unroll
        for (int r = 0; r < 4; r++) {
            float m = 0.f, ps = 0.f, pd = 0.f;
            #pragma unroll
            for (int jj = 0; jj < 4; jj++) {
                float v = acc[i][jj][r];
                m = fmaxf(m, fabsf(v));
                ps = fmaf(v, asc[jj], ps);
                pd = fmaf(v, adc[jj], pd);
            }
            #pragma unroll
            for (int d = 1; d < 16; d <<= 1) {
                m = fmaxf(m, __shfl_xor(m, d));
                ps += __shfl_xor(ps, d);
                pd += __shfl_xor(pd, d);
            }
            if ((lane & 15) == 0) {
                int row = wr * MI * 16 + i * 16 + (lane >> 4) * 4 + r;
                s_red[0][wc][row] = m;
                s_red[1][wc][row] = ps;
                s_red[2][wc][row] = pd;
            }
        }
    }
    __syncthreads();
    if (t < BM) {
        float rm = fmaxf(fmaxf(s_red[0][0][t], s_red[0][1][t]), 1e-30f);
        s_rs[t] = 127.f / rm;
        int node = r0 + t;
        side[(size_t)node * (2 * H) + hb]     = s_red[1][0][t] + s_red[1][1][t];
        side[(size_t)node * (2 * H) + H + hb] = rm * (1.f / 127.f);
        avd[(size_t)node * H + hb]            = s_red[2][0][t] + s_red[2][1][t];
    }
    __syncthreads();
    #pragma unroll
    for (int i = 0; i < MI; i++)
        #pragma unroll
        for (int jj = 0; jj < 4; jj++)
            #pragma unroll
            for (int r = 0; r < 4; r++) {
                int row = wr * MI * 16 + i * 16 + (lane >> 4) * 4 + r;
                int col = wc * 64 + jj * 16 + (lane & 15);
                int qi = (int)rintf(acc[i][jj][r] * s_rs[row]) + 128;
                qi = min(255, max(0, qi));
                s_q[row * 144 + col] = (uchar_t)qi;
            }
    __syncthreads();
    #pragma unroll
    for (int p2 = 0; p2 < BM / 32; p2++) {
        int idx = p2 * 256 + t;
        int row = idx >> 3, ch = idx & 7;
        *(uint4*)(Cq + (size_t)(r0 + row) * Nc + c0 + ch * 16) =
            *(const uint4*)(s_q + row * 144 + ch * 16);
    }
}

// ---------------- single-pass edge softmax + aggregation over int8 features ----------------
// Group-of-8 readlane-batched gathers (8 loads in flight/wave); den/Ssum accumulated
// redundantly by every lane from LDS broadcasts (no cross-lane reduce at all).
template<int H, int TOT, bool OUT_BF16>
__global__ __launch_bounds__(256) void agg_q(const int* __restrict__ off,
                                             const int* __restrict__ csr,
                                             const uchar_t* __restrict__ fq,
                                             const float* __restrict__ side,
                                             const float* __restrict__ avd,
                                             const float* __restrict__ bias,
                                             void* __restrict__ outv, int n) {
    constexpr int J = TOT / 64;          // bytes per lane per edge
    __shared__ float s_e[4][64 * H];     // raw exp
    __shared__ float s_es[4][64 * H];    // exp * src row scale
    int w = threadIdx.x >> 6, lane = threadIdx.x & 63;
    int dst = blockIdx.x * 4 + w;
    if (dst >= n) return;
    const int h_own = (H == 1) ? 0 : (lane >> 4);
    float adv[H];
    if constexpr (H == 4) {
        f4 t4 = *(const f4*)&avd[(size_t)dst * 4];
        #pragma unroll
        for (int h = 0; h < 4; h++) adv[h] = t4[h];
    } else {
        adv[0] = avd[dst];
    }
    int beg = off[dst], end = off[dst + 1];
    float den = 0.f, Ssum = 0.f;
    float acc[J] = {};
    float* ew  = s_e[w];
    float* esw = s_es[w];

    for (int b = beg; b < end; b += 64) {
        int idx = b + lane;
        bool val = idx < end;
        int sv = val ? csr[idx] : 0;
        unsigned myoff = (unsigned)sv * TOT;
        if constexpr (H == 4) {
            const f4* sp = (const f4*)(side + (size_t)sv * 8);
            f4 av = sp[0], sc = sp[1];
            f4 ev, esv;
            #pragma unroll
            for (int h = 0; h < 4; h++) {
                float l = av[h] + adv[h];
                l = fmaxf(l, l * NEG_SLOPE);           // leaky_relu (slope<1)
                float e = val ? __expf(l) : 0.f;
                ev[h] = e;
                esv[h] = e * sc[h];
            }
            *(f4*)&ew[lane * 4]  = ev;
            *(f4*)&esw[lane * 4] = esv;
        } else {
            float2 sp = *(const float2*)(side + (size_t)sv * 2);
            float l = sp.x + adv[0];
            l = fmaxf(l, l * NEG_SLOPE);
            float e = val ? __expf(l) : 0.f;
            ew[lane]  = e;
            esw[lane] = e * sp.y;
        }
        asm volatile("s_waitcnt lgkmcnt(0)" ::: "memory");
        int cnt = min(64, end - b);
        for (int jb = 0; jb < cnt; jb += 8) {
            // issue 8 independent gathers via scalar (readlane) offsets
            uint2 u8v[8];
            unsigned us16[8];
            #pragma unroll
            for (int q = 0; q < 8; q++) {
                unsigned o = (unsigned)__builtin_amdgcn_readlane((int)myoff, jb + q);
                if constexpr (J == 8) {
                    u8v[q] = *(const uint2*)(fq + o + lane * 8);
                } else {
                    us16[q] = *(const ushort_t*)(fq + o + lane * 2);
                }
            }
            #pragma unroll
            for (int q = 0; q < 8; q++) {
                int j = jb + q;
                float e  = ew[j * H + h_own];
                float es = esw[j * H + h_own];
                den += e;
                Ssum += es;
                if constexpr (J == 8) {
                    float b0, b1, b2, b3;
                    cvt4(u8v[q].x, b0, b1, b2, b3);
                    acc[0] = fmaf(es, b0, acc[0]);
                    acc[1] = fmaf(es, b1, acc[1]);
                    acc[2] = fmaf(es, b2, acc[2]);
                    acc[3] = fmaf(es, b3, acc[3]);
                    cvt4(u8v[q].y, b0, b1, b2, b3);
                    acc[4] = fmaf(es, b0, acc[4]);
                    acc[5] = fmaf(es, b1, acc[5]);
                    acc[6] = fmaf(es, b2, acc[6]);
                    acc[7] = fmaf(es, b3, acc[7]);
                } else {
                    float b0, b1;
                    asm("v_cvt_f32_ubyte0 %0, %1" : "=v"(b0) : "v"(us16[q]));
                    asm("v_cvt_f32_ubyte1 %0, %1" : "=v"(b1) : "v"(us16[q]));
                    acc[0] = fmaf(es, b0, acc[0]);
                    acc[1] = fmaf(es, b1, acc[1]);
                }
            }
        }
    }
    float rden = 1.f / den;
    if constexpr (OUT_BF16) {
        unsigned short ov[J];
        #pragma unroll
        for (int u = 0; u < J; u++) {
            float v = (acc[u] - 128.f * Ssum) * rden + bias[lane * J + u];
            v = v > 0.f ? v : expm1f(v);
            ov[u] = f2bf(v);
        }
        *(short8*)((ushort_t*)outv + (size_t)dst * TOT + lane * J) = *(short8*)ov;
    } else {
        float v0 = (acc[0] - 128.f * Ssum) * rden + bias[lane * 2];
        float v1 = (acc[1] - 128.f * Ssum) * rden + bias[lane * 2 + 1];
        v0 = v0 > 0.f ? v0 : expm1f(v0);
        v1 = v1 > 0.f ? v1 : expm1f(v1);
        float2 vv = make_float2(v0, v1);
        *(float2*)((float*)outv + (size_t)dst * TOT + lane * 2) = vv;
    }
}

// ---------------- pooling (batch sorted -> run-compressed atomics) + head ----------------
__global__ __launch_bounds__(256) void pool_kernel(const float* __restrict__ feat,
                                                   const int* __restrict__ batch,
                                                   float* __restrict__ gsum, int n) {
    int t = threadIdx.x;
    int ch = t & 127, half = t >> 7;
    int base = blockIdx.x * 64;
    float acc = 0.f;
    int curg = -1;
    for (int k = half; k < 64; k += 2) {
        int node = base + k;
        if (node >= n) break;
        int g = batch[node];
        if (g != curg) {
            if (curg >= 0) atomicAdd(&gsum[(size_t)curg * 128 + ch], acc);
            acc = 0.f;
            curg = g;
        }
        acc += feat[(size_t)node * 128 + ch];
    }
    if (curg >= 0) atomicAdd(&gsum[(size_t)curg * 128 + ch], acc);
}

__global__ __launch_bounds__(256) void final_kernel(const float* __restrict__ gsum,
                                                    const int* __restrict__ gcnt,
                                                    const float* __restrict__ Wl,
                                                    const float* __restrict__ bl,
                                                    float* __restrict__ out, int g_total) {
    int w = threadIdx.x >> 6, lane = threadIdx.x & 63;
    int g = blockIdx.x * 4 + w;
    if (g >= g_total) return;
    float inv = 1.f / fmaxf((float)gcnt[g], 1.f);
    float p = 0.f;
    #pragma unroll
    for (int j = 0; j < 2; j++) {
        int ch = lane + 64 * j;
        p += gsum[(size_t)g * 128 + ch] * Wl[ch];
    }
    #pragma unroll
    for (int d = 32; d; d >>= 1) p += __shfl_xor(p, d);
    if (lane == 0) out[g] = p * inv + bl[0];
}

extern "C" void kernel_launch(void* const* d_in, const int* in_sizes, int n_in,
                              void* d_out, int out_size, void* d_ws, size_t ws_size,
                              hipStream_t stream) {
    const float* x   = (const float*)d_in[0];
    const int*   ei  = (const int*)d_in[1];
    const int*   bat = (const int*)d_in[2];
    const float* W1  = (const float*)d_in[3];
    const float* as1 = (const float*)d_in[4];
    const float* ad1 = (const float*)d_in[5];
    const float* b1  = (const float*)d_in[6];
    const float* W2  = (const float*)d_in[7];
    const float* as2 = (const float*)d_in[8];
    const float* ad2 = (const float*)d_in[9];
    const float* b2  = (const float*)d_in[10];
    const float* Wl  = (const float*)d_in[11];
    const float* bl  = (const float*)d_in[12];
    float* out = (float*)d_out;

    const int N    = in_sizes[0] / 128;
    const int E    = in_sizes[1] / 2;
    const int Et   = E + N;
    const int G    = 512;
    const int Mpad = (N + 127) & ~127;
    const int nb   = (N + 1023) >> 10;

    char* p = (char*)d_ws;
    auto alloc = [&](size_t bytes) { char* r = p; p += (bytes + 255) & ~(size_t)255; return r; };
    ushort_t* xb    = (ushort_t*)alloc((size_t)Mpad * 128 * 2);
    ushort_t* W1t   = (ushort_t*)alloc((size_t)512 * 128 * 2);
    ushort_t* W2t   = (ushort_t*)alloc((size_t)128 * 512 * 2);
    uchar_t*  h1q   = (uchar_t*)alloc((size_t)Mpad * 512);
    ushort_t* hb    = (ushort_t*)alloc((size_t)Mpad * 512 * 2);
    uchar_t*  h2q   = (uchar_t*)alloc((size_t)Mpad * 128);
    float*    feat2 = (float*)alloc((size_t)N * 128 * 4);
    float*    side1 = (float*)alloc((size_t)Mpad * 8 * 4);
    float*    avd1  = (float*)alloc((size_t)Mpad * 4 * 4);
    float*    side2 = (float*)alloc((size_t)Mpad * 2 * 4);
    float*    avd2  = (float*)alloc((size_t)Mpad * 4);
    // ---- zeroed block (one memset) ----
    float*    gsum  = (float*)alloc((size_t)G * 128 * 4);
    int*      gcnt  = (int*)alloc((size_t)G * 4);
    int*      deg   = (int*)alloc((size_t)N * 4);
    // ---- end zeroed block ----
    int*      off   = (int*)alloc((size_t)(N + 1) * 4);
    int*      cur   = (int*)alloc((size_t)N * 4);
    int*      btot  = (int*)alloc((size_t)128 * 4);
    int*      csr   = (int*)alloc((size_t)Et * 4);

    hipMemsetAsync(gsum, 0, (size_t)((char*)off - (char*)gsum), stream);
    hipMemsetAsync(hb + (size_t)N * 512, 0, (size_t)(Mpad - N) * 512 * 2, stream);

    // prep (casts + degree hist), then CSR
    const int prep_n = Mpad * 128 + 2 * 65536;
    prep_kernel<<<(prep_n + 255) / 256, 256, 0, stream>>>(x, W1, W2, xb, W1t, W2t,
                                                          ei, deg, N * 128, Mpad * 128, E, Et);
    scan_local<<<nb, 1024, 0, stream>>>(deg, off, btot, N);
    scan_add<<<(N + 256) / 256, 256, 0, stream>>>(btot, off, cur, bat, gcnt, N, nb);
    scatter_kernel<<<(Et + 255) / 256, 256, 0, stream>>>(ei, E, Et, cur, csr);

    // Layer 1: GEMM (+per-head int8 quant + fused avec), then softmax-aggregate (+bias+ELU)
    gemm_q<4, 4><<<dim3(Mpad / 128, 4), 256, 0, stream>>>(xb, W1t, h1q, as1, ad1, side1, avd1, 128);
    agg_q<4, 512, true><<<(N + 3) / 4, 256, 0, stream>>>(off, csr, h1q, side1, avd1, b1, hb, N);

    // Layer 2 (BM=64 -> 782 blocks for load balance)
    gemm_q<2, 1><<<dim3(Mpad / 64, 1), 256, 0, stream>>>(hb, W2t, h2q, as2, ad2, side2, avd2, 512);
    agg_q<1, 128, false><<<(N + 3) / 4, 256, 0, stream>>>(off, csr, h2q, side2, avd2, b2, feat2, N);

    // Pool + head
    pool_kernel<<<(N + 63) / 64, 256, 0, stream>>>(feat2, bat, gsum, N);
    final_kernel<<<(G + 3) / 4, 256, 0, stream>>>(gsum, gcnt, Wl, bl, out, G);
}